// Round 14
// baseline (2031.013 us; speedup 1.0000x reference)
//
#include <hip/hip_runtime.h>
#include <math.h>

#define LOG2E 1.4426950408889634f

typedef float v2f __attribute__((ext_vector_type(2)));

// ---------------------------------------------------------------------------
// prep_csc: padded CSC of recurrent synapses, split into a register part
// [col][quarter(4)][12] (ent_g) and an overflow part [col][quarter][4] (ov_g)
// for columns with cnt>48 (~3%). entry {p=-sigma*log2e, q=sigma*mu*log2e,
// s=softplus(w)*erev, w=i*8 (byte offset into float2 state)}. Zero-padded ->
// exact no-op. Within a quarter, entries sorted by ((i&15)-slot16)&15 where
// slot16 = ((rank&3)<<2)|q: step-k b64 pair-banks rotate across the wave.
// meta: [0..127]=cnt by col, [128..255]=perm (rank-sorted desc by cnt).
// ---------------------------------------------------------------------------
__global__ __launch_bounds__(128)
void lnn_prep_csc(const float* __restrict__ sigma, const float* __restrict__ mu,
                  const float* __restrict__ w, const float* __restrict__ erev,
                  const float* __restrict__ mask,
                  float4* __restrict__ ent_g, float4* __restrict__ ov_g,
                  int* __restrict__ meta_g)
{
    __shared__ int cnt_s[128], rank_s[128];
    const int j = threadIdx.x;
    int cnt = 0;
    for (int i = 0; i < 128; ++i) cnt += (mask[i * 128 + j] != 0.0f) ? 1 : 0;
    cnt_s[j] = cnt;
    __syncthreads();
    int rank = 0;
    for (int i = 0; i < 128; ++i) {
        int ci = cnt_s[i];
        rank += (ci > cnt || (ci == cnt && i < j)) ? 1 : 0;
    }
    meta_g[j] = cnt;
    meta_g[128 + rank] = j;
    rank_s[j] = rank;
    __syncthreads();

    float4 z; z.x = 0.f; z.y = 0.f; z.z = 0.f; z.w = __int_as_float(0);
    for (int q = 0; q < 4; ++q) {
        for (int k = 0; k < 12; ++k) ent_g[(j * 4 + q) * 12 + k] = z;
        for (int k = 0; k < 4; ++k)  ov_g[(j * 4 + q) * 4 + k] = z;
    }

    for (int q = 0; q < 4; ++q) {
        int idxs[16];
        int m = 0, c = 0;
        for (int i = 0; i < 128; ++i) {
            if (mask[i * 128 + j] != 0.0f) {
                if ((c & 3) == q && m < 16) idxs[m++] = i;
                ++c;
            }
        }
        const int slot = ((rank_s[j] & 3) << 2) | q;
        for (int a = 1; a < m; ++a) {            // insertion sort by pair-bank key
            int v = idxs[a];
            int kv = ((v & 15) - slot) & 15;
            int bp = a;
            while (bp > 0) {
                int u = idxs[bp - 1];
                if ((((u & 15) - slot) & 15) <= kv) break;
                idxs[bp] = u; --bp;
            }
            idxs[bp] = v;
        }
        for (int k = 0; k < m; ++k) {
            int i = idxs[k];
            int gi = i * 128 + j;
            float sg = sigma[gi], mm = mu[gi];
            float4 e;
            e.x = -sg * LOG2E;
            e.y = sg * mm * LOG2E;
            e.z = log1pf(expf(w[gi])) * erev[gi];
            e.w = __int_as_float(i << 3);        // byte offset into float2 state
            if (k < 12) ent_g[(j * 4 + q) * 12 + k] = e;
            else        ov_g[(j * 4 + q) * 4 + (k - 12)] = e;
        }
    }
}

// ---------------------------------------------------------------------------
// prep_sens: sensory synapse constants (6x128).
// ---------------------------------------------------------------------------
__global__ __launch_bounds__(768)
void lnn_prep_sens(const float* __restrict__ ssig, const float* __restrict__ smu,
                   const float* __restrict__ sw, const float* __restrict__ serev,
                   const float* __restrict__ smask,
                   float* __restrict__ g_sp, float* __restrict__ g_sq,
                   float* __restrict__ g_ss)
{
    int idx = threadIdx.x;
    float sg = ssig[idx], m = smu[idx];
    g_sp[idx] = -sg * LOG2E;
    g_sq[idx] = sg * m * LOG2E;
    g_ss[idx] = log1pf(expf(sw[idx])) * smask[idx] * serev[idx];
}

// ---------------------------------------------------------------------------
// prep2: LayerNorm(6) + input affine folded -> inp [B*T][6].
// ---------------------------------------------------------------------------
__global__ void lnn_prep2(const float* __restrict__ x,
                          const float* __restrict__ ln_g, const float* __restrict__ ln_b,
                          const float* __restrict__ in_w, const float* __restrict__ in_b,
                          float* __restrict__ inp)
{
    int r = blockIdx.x * 256 + threadIdx.x;
    if (r >= 1024 * 96) return;
    const float* xp = x + r * 6;
    float v[6];
#pragma unroll
    for (int k = 0; k < 6; ++k) v[k] = xp[k];
    float m = (v[0] + v[1] + v[2] + v[3] + v[4] + v[5]) * (1.0f / 6.0f);
    float var = 0.f;
#pragma unroll
    for (int k = 0; k < 6; ++k) { float d = v[k] - m; var = fmaf(d, d, var); }
    var *= (1.0f / 6.0f);
    float rs = rsqrtf(var + 1e-5f);
    float* op = inp + r * 6;
#pragma unroll
    for (int k = 0; k < 6; ++k)
        op[k] = fmaf(fmaf((v[k] - m) * rs, ln_g[k], ln_b[k]), in_w[k], in_b[k]);
}

// ---------------------------------------------------------------------------
// main: R13 structure (512 blocks x 512 threads, 2 batch/block, 12 pinned
// entries + LDS overflow, b64 gather, dbuf, 1 barrier/unfold) with the
// two-batch algebra written in ext_vector float2 so the backend can emit
// VOP3P packed f32 (v_pk_fma/v_pk_add, scalar broadcast via op_sel) — the
// 11 scalar VALU instrs per entry are naturally 5-6 packed ones.
// ---------------------------------------------------------------------------
__global__ __launch_bounds__(512, 4)
void lnn_main_sp2(const float* __restrict__ inp, const float4* __restrict__ ent_g,
                  const float4* __restrict__ ov_g, const int* __restrict__ meta_g,
                  const float* __restrict__ g_sp, const float* __restrict__ g_sq,
                  const float* __restrict__ g_ss,
                  const float* __restrict__ g_gleak, const float* __restrict__ g_vleak,
                  const float* __restrict__ g_cm,
                  const float* __restrict__ g_ow, const float* __restrict__ g_ob,
                  float* __restrict__ outs)
{
    __shared__ v2f vb2[2][128];                    // [buf][i] = (v_b0, v_b1)
    __shared__ float4 ov_s[2048];                  // overflow entries, 32KB
    __shared__ float sp_s[6 * 132], sq_s[6 * 132], ss_s[6 * 132];
    __shared__ float cmt_s[128], gl_s[128], glvl_s[128];
    __shared__ float ow_s[64], ob_s[64];

    const int tid = threadIdx.x;
    const int j_slot = tid >> 2;
    const int q = tid & 3;
    const int jj = meta_g[128 + j_slot];
    const int cnt = meta_g[jj];
    const int kq_lane = (cnt + 3 - q) >> 2;

    if (tid < 512) ((float*)vb2)[tid] = 0.f;
    for (int i = tid; i < 2048; i += 512) ov_s[i] = ov_g[i];
    for (int idx = tid; idx < 768; idx += 512) {
        int k = idx >> 7, j = idx & 127;
        sp_s[k * 132 + j] = g_sp[idx];
        sq_s[k * 132 + j] = g_sq[idx];
        ss_s[k * 132 + j] = g_ss[idx];
    }
    if (tid < 128) {
        cmt_s[tid] = log1pf(expf(g_cm[tid])) * 6.0f;
        float gl = log1pf(expf(g_gleak[tid]));
        gl_s[tid] = gl;
        glvl_s[tid] = gl * g_vleak[tid];
    }
    if (tid < 64) { ow_s[tid] = g_ow[tid]; ob_s[tid] = g_ob[tid]; }

    // 12 entries -> named registers (zero-padded), pinned against remat (R8).
    const float4* eg = ent_g + ((jj << 2) + q) * 12;
#define ENT_LOAD(K) float4 e##K = eg[K];
    ENT_LOAD(0) ENT_LOAD(1) ENT_LOAD(2)  ENT_LOAD(3)
    ENT_LOAD(4) ENT_LOAD(5) ENT_LOAD(6)  ENT_LOAD(7)
    ENT_LOAD(8) ENT_LOAD(9) ENT_LOAD(10) ENT_LOAD(11)
#define ENT_PIN(K) asm volatile("" : "+v"(e##K.x), "+v"(e##K.y), "+v"(e##K.z), "+v"(e##K.w));
    ENT_PIN(0) ENT_PIN(1) ENT_PIN(2)  ENT_PIN(3)
    ENT_PIN(4) ENT_PIN(5) ENT_PIN(6)  ENT_PIN(7)
    ENT_PIN(8) ENT_PIN(9) ENT_PIN(10) ENT_PIN(11)

    // wave-uniform trip count (<=16)
    int kqm = kq_lane;
#pragma unroll
    for (int m = 1; m < 64; m <<= 1) kqm = max(kqm, __shfl_xor(kqm, m));
    kqm = __builtin_amdgcn_readfirstlane(kqm);

    __syncthreads();

    const float cmt = cmt_s[jj], glf = gl_s[jj], glvl = glvl_s[jj];
    const float osc = (jj < 64) ? ow_s[jj] : 0.f;
    const float obi = (jj < 64) ? ob_s[jj] : 0.f;
    const int bg = blockIdx.x;
    const float* ip0 = inp + (bg * 2) * 576;
    const float* ip1 = ip0 + 576;
    float* orow0 = outs + (((bg * 2) * 96) << 6) + jj;
    v2f vcur2 = {0.f, 0.f};
    const char* vbc = (const char*)&vb2[0][0];
    const int ovbase = ((jj << 2) + q) << 2;

    // one entry, both batch elems, packed algebra:
    // z-pair fma, E-pair exp2, +1 pair add, 1 rcp, swapped-mul pair, 2 accum fmas.
#define SIG_BODY(EX, EY, EZ, EAZ, EW, OFS) { \
        v2f vv = *(const v2f*)(vbc + (OFS) + __float_as_int(EW)); \
        v2f z = EX * vv + EY; \
        v2f E; \
        E.x = __builtin_amdgcn_exp2f(z.x); \
        E.y = __builtin_amdgcn_exp2f(z.y); \
        v2f AB = E + 1.0f; \
        float rP = __builtin_amdgcn_rcpf(AB.x * AB.y); \
        v2f s = __builtin_shufflevector(AB, AB, 1, 0) * rP; \
        n01 += EZ * s; \
        d01 += EAZ * s; }

#define ENT_DO(K, OFS) if (kqm > K) SIG_BODY(e##K.x, e##K.y, e##K.z, fabsf(e##K.z), e##K.w, OFS)
#define OV_DO(K, OFS)  if (kqm > 12 + K) { float4 ee = ov_s[ovbase + K]; \
        SIG_BODY(ee.x, ee.y, ee.z, fabsf(ee.z), ee.w, OFS) }

#define ENT_BLOCK(OFS) \
        ENT_DO(0, OFS) ENT_DO(1, OFS) ENT_DO(2, OFS)  ENT_DO(3, OFS) \
        ENT_DO(4, OFS) ENT_DO(5, OFS) ENT_DO(6, OFS)  ENT_DO(7, OFS) \
        ENT_DO(8, OFS) ENT_DO(9, OFS) ENT_DO(10, OFS) ENT_DO(11, OFS) \
        OV_DO(0, OFS)  OV_DO(1, OFS)  OV_DO(2, OFS)   OV_DO(3, OFS)

    for (int t = 0; t < 96; ++t) {
        // sensory: q handles k=q (both elems) and q<2 also k=q+4; packed.
        v2f sn01 = {0.f, 0.f}, sd01 = {0.f, 0.f};
        {
            const int ko = q * 132 + jj;
            v2f xin; xin.x = ip0[q]; xin.y = ip1[q];
            v2f z = sp_s[ko] * xin + sq_s[ko];
            v2f E;
            E.x = __builtin_amdgcn_exp2f(z.x);
            E.y = __builtin_amdgcn_exp2f(z.y);
            v2f AB = E + 1.0f;
            float rP = __builtin_amdgcn_rcpf(AB.x * AB.y);
            v2f s = __builtin_shufflevector(AB, AB, 1, 0) * rP;
            float sv = ss_s[ko];
            sn01 += sv * s;
            sd01 += fabsf(sv) * s;
            if (q < 2) {
                const int k2 = q + 4;
                const int k2o = k2 * 132 + jj;
                v2f xin2; xin2.x = ip0[k2]; xin2.y = ip1[k2];
                v2f z2 = sp_s[k2o] * xin2 + sq_s[k2o];
                v2f E2;
                E2.x = __builtin_amdgcn_exp2f(z2.x);
                E2.y = __builtin_amdgcn_exp2f(z2.y);
                v2f AB2 = E2 + 1.0f;
                float rP2 = __builtin_amdgcn_rcpf(AB2.x * AB2.y);
                v2f s2 = __builtin_shufflevector(AB2, AB2, 1, 0) * rP2;
                float sv2 = ss_s[k2o];
                sn01 += sv2 * s2;
                sd01 += fabsf(sv2) * s2;
            }
        }
        sn01.x += __shfl_xor(sn01.x, 1); sd01.x += __shfl_xor(sd01.x, 1);
        sn01.y += __shfl_xor(sn01.y, 1); sd01.y += __shfl_xor(sd01.y, 1);
        sn01.x += __shfl_xor(sn01.x, 2); sd01.x += __shfl_xor(sd01.x, 2);
        sn01.y += __shfl_xor(sn01.y, 2); sd01.y += __shfl_xor(sd01.y, 2);
        ip0 += 6; ip1 += 6;

        // 6 unfolds; u even: read buf0 write buf1; odd: read buf1 write buf0.
        for (int u = 0; u < 6; ++u) {
            v2f n01 = {0.f, 0.f}, d01 = {0.f, 0.f};
            if (u & 1) { ENT_BLOCK(1024) } else { ENT_BLOCK(0) }
            n01.x += __shfl_xor(n01.x, 1); d01.x += __shfl_xor(d01.x, 1);
            n01.y += __shfl_xor(n01.y, 1); d01.y += __shfl_xor(d01.y, 1);
            n01.x += __shfl_xor(n01.x, 2); d01.x += __shfl_xor(d01.x, 2);
            n01.y += __shfl_xor(n01.y, 2); d01.y += __shfl_xor(d01.y, 2);
            v2f num = cmt * vcur2 + glvl;
            num += n01 + sn01;
            v2f den = (cmt + glf) + d01 + sd01;
            float rD = __builtin_amdgcn_rcpf(den.x * den.y);   // den >= 3.1 each
            vcur2 = num * __builtin_shufflevector(den, den, 1, 0) * rD;
            if (q == 0) {
                *(v2f*)((char*)vb2 + (((u & 1) ^ 1) << 10) + (jj << 3)) = vcur2;
                if (u == 5 && jj < 64) {
                    orow0[0] = fmaf(vcur2.x, osc, obi);
                    orow0[6144] = fmaf(vcur2.y, osc, obi);
                }
            }
            __syncthreads();   // single barrier: writes visible, old-buf reads done
        }
        orow0 += 64;
    }
}

// ---------------------------------------------------------------------------
// attention pooling over T + classifier, one block per batch element.
// ---------------------------------------------------------------------------
__global__ __launch_bounds__(128)
void lnn_attn(const float* __restrict__ outs,
              const float* __restrict__ aw1, const float* __restrict__ ab1,
              const float* __restrict__ aw2,
              const float* __restrict__ cw1, const float* __restrict__ cb1,
              const float* __restrict__ cw2, const float* __restrict__ cb2,
              float* __restrict__ out)
{
    __shared__ float o_s[96 * 65];
    __shared__ float aw1_s[64 * 32];
    __shared__ float scr[96], attw[96], ctx_s[64], h2_s[128];

    const int b = blockIdx.x, tid = threadIdx.x;
    const float* ob = outs + b * 6144;
    for (int idx = tid; idx < 6144; idx += 128)
        o_s[(idx >> 6) * 65 + (idx & 63)] = ob[idx];
    for (int idx = tid; idx < 2048; idx += 128)
        aw1_s[idx] = aw1[idx];
    __syncthreads();

    if (tid < 96) {
        float h1[32];
#pragma unroll
        for (int m = 0; m < 32; ++m) h1[m] = ab1[m];
        for (int jj = 0; jj < 64; ++jj) {
            float ov = o_s[tid * 65 + jj];
#pragma unroll
            for (int m = 0; m < 32; ++m) h1[m] = fmaf(ov, aw1_s[(jj << 5) + m], h1[m]);
        }
        float sc = 0.f;
#pragma unroll
        for (int m = 0; m < 32; ++m) sc = fmaf(fmaxf(h1[m], 0.f), aw2[m], sc);
        scr[tid] = sc;
    }
    __syncthreads();

    float mx = -1e30f;
    for (int k = 0; k < 96; ++k) mx = fmaxf(mx, scr[k]);
    float sum = 0.f;
    for (int k = 0; k < 96; ++k) sum += expf(scr[k] - mx);
    if (tid < 96) attw[tid] = expf(scr[tid] - mx) / sum;
    __syncthreads();

    if (tid < 64) {
        float c = 0.f;
        for (int k = 0; k < 96; ++k) c = fmaf(attw[k], o_s[k * 65 + tid], c);
        ctx_s[tid] = c;
    }
    __syncthreads();

    {
        float a = cb1[tid];
        for (int jj = 0; jj < 64; ++jj) a = fmaf(ctx_s[jj], cw1[(jj << 7) + tid], a);
        h2_s[tid] = fmaxf(a, 0.f);
    }
    __syncthreads();

    if (tid < 100) {
        float a = cb2[tid];
        for (int m = 0; m < 128; ++m) a = fmaf(h2_s[m], cw2[m * 100 + tid], a);
        out[b * 100 + tid] = a;
    }
}

// ---------------------------------------------------------------------------
extern "C" void kernel_launch(void* const* d_in, const int* in_sizes, int n_in,
                              void* d_out, int out_size, void* d_ws, size_t ws_size,
                              hipStream_t stream)
{
    const float* x     = (const float*)d_in[0];
    const float* ln_g  = (const float*)d_in[1];
    const float* ln_b  = (const float*)d_in[2];
    const float* gleak = (const float*)d_in[3];
    const float* vleak = (const float*)d_in[4];
    const float* cm    = (const float*)d_in[5];
    const float* sigma = (const float*)d_in[6];
    const float* mu    = (const float*)d_in[7];
    const float* w     = (const float*)d_in[8];
    const float* erev  = (const float*)d_in[9];
    const float* ssig  = (const float*)d_in[10];
    const float* smu   = (const float*)d_in[11];
    const float* sw    = (const float*)d_in[12];
    const float* serev = (const float*)d_in[13];
    const float* in_w  = (const float*)d_in[14];
    const float* in_b  = (const float*)d_in[15];
    const float* ow    = (const float*)d_in[16];
    const float* obb   = (const float*)d_in[17];
    const float* aw1   = (const float*)d_in[18];
    const float* ab1   = (const float*)d_in[19];
    const float* aw2   = (const float*)d_in[20];
    const float* cw1   = (const float*)d_in[21];
    const float* cb1   = (const float*)d_in[22];
    const float* cw2   = (const float*)d_in[23];
    const float* cb2   = (const float*)d_in[24];
    const float* mask  = (const float*)d_in[25];
    const float* smask = (const float*)d_in[26];

    float* ws = (float*)d_ws;
    float*  inp   = ws;                          // 589824 f
    float*  sp    = ws + 589824;                 // 768
    float*  sq    = ws + 590592;                 // 768
    float*  ss    = ws + 591360;                 // 768
    float4* ent_g = (float4*)(ws + 592128);      // 128*4*12 float4 = 24576 f
    float4* ov_g  = (float4*)(ws + 616704);      // 128*4*4 float4  = 8192 f
    int*    meta  = (int*)(ws + 624896);         // 256 ints (pad 512)
    float*  outs  = ws + 625408;                 // 6291456 f

    lnn_prep_csc<<<1, 128, 0, stream>>>(sigma, mu, w, erev, mask, ent_g, ov_g, meta);
    lnn_prep_sens<<<1, 768, 0, stream>>>(ssig, smu, sw, serev, smask, sp, sq, ss);
    lnn_prep2<<<384, 256, 0, stream>>>(x, ln_g, ln_b, in_w, in_b, inp);
    lnn_main_sp2<<<512, 512, 0, stream>>>(inp, ent_g, ov_g, meta, sp, sq, ss,
                                          gleak, vleak, cm, ow, obb, outs);
    lnn_attn<<<1024, 128, 0, stream>>>(outs, aw1, ab1, aw2, cw1, cb1, cw2, cb2,
                                       (float*)d_out);
}

// Round 16
// 1179.232 us; speedup vs baseline: 1.7223x; 1.7223x over previous
//
#include <hip/hip_runtime.h>
#include <math.h>

#define LOG2E 1.4426950408889634f

// ---------------------------------------------------------------------------
// prep_csc: padded CSC of recurrent synapses, split into a register part
// [col][quarter(4)][12] (ent_g) and an overflow part [col][quarter][4] (ov_g)
// for columns with cnt>48 (~3%). entry {p=-sigma*log2e, q=sigma*mu*log2e,
// s=softplus(w)*erev, w=i*8 (byte offset into float2 state)}. Zero-padded ->
// exact no-op. Within a quarter, entries sorted by ((i&15)-slot16)&15 where
// slot16 = ((rank&3)<<2)|q: step-k b64 pair-banks rotate across the wave.
// meta: [0..127]=cnt by col, [128..255]=perm (rank-sorted desc by cnt).
// ---------------------------------------------------------------------------
__global__ __launch_bounds__(128)
void lnn_prep_csc(const float* __restrict__ sigma, const float* __restrict__ mu,
                  const float* __restrict__ w, const float* __restrict__ erev,
                  const float* __restrict__ mask,
                  float4* __restrict__ ent_g, float4* __restrict__ ov_g,
                  int* __restrict__ meta_g)
{
    __shared__ int cnt_s[128], rank_s[128];
    const int j = threadIdx.x;
    int cnt = 0;
    for (int i = 0; i < 128; ++i) cnt += (mask[i * 128 + j] != 0.0f) ? 1 : 0;
    cnt_s[j] = cnt;
    __syncthreads();
    int rank = 0;
    for (int i = 0; i < 128; ++i) {
        int ci = cnt_s[i];
        rank += (ci > cnt || (ci == cnt && i < j)) ? 1 : 0;
    }
    meta_g[j] = cnt;
    meta_g[128 + rank] = j;
    rank_s[j] = rank;
    __syncthreads();

    float4 z; z.x = 0.f; z.y = 0.f; z.z = 0.f; z.w = __int_as_float(0);
    for (int q = 0; q < 4; ++q) {
        for (int k = 0; k < 12; ++k) ent_g[(j * 4 + q) * 12 + k] = z;
        for (int k = 0; k < 4; ++k)  ov_g[(j * 4 + q) * 4 + k] = z;
    }

    for (int q = 0; q < 4; ++q) {
        int idxs[16];
        int m = 0, c = 0;
        for (int i = 0; i < 128; ++i) {
            if (mask[i * 128 + j] != 0.0f) {
                if ((c & 3) == q && m < 16) idxs[m++] = i;
                ++c;
            }
        }
        const int slot = ((rank_s[j] & 3) << 2) | q;
        for (int a = 1; a < m; ++a) {            // insertion sort by pair-bank key
            int v = idxs[a];
            int kv = ((v & 15) - slot) & 15;
            int bp = a;
            while (bp > 0) {
                int u = idxs[bp - 1];
                if ((((u & 15) - slot) & 15) <= kv) break;
                idxs[bp] = u; --bp;
            }
            idxs[bp] = v;
        }
        for (int k = 0; k < m; ++k) {
            int i = idxs[k];
            int gi = i * 128 + j;
            float sg = sigma[gi], mm = mu[gi];
            float4 e;
            e.x = -sg * LOG2E;
            e.y = sg * mm * LOG2E;
            e.z = log1pf(expf(w[gi])) * erev[gi];
            e.w = __int_as_float(i << 3);        // byte offset into float2 state
            if (k < 12) ent_g[(j * 4 + q) * 12 + k] = e;
            else        ov_g[(j * 4 + q) * 4 + (k - 12)] = e;
        }
    }
}

// ---------------------------------------------------------------------------
// prep_sens: sensory synapse constants (6x128).
// ---------------------------------------------------------------------------
__global__ __launch_bounds__(768)
void lnn_prep_sens(const float* __restrict__ ssig, const float* __restrict__ smu,
                   const float* __restrict__ sw, const float* __restrict__ serev,
                   const float* __restrict__ smask,
                   float* __restrict__ g_sp, float* __restrict__ g_sq,
                   float* __restrict__ g_ss)
{
    int idx = threadIdx.x;
    float sg = ssig[idx], m = smu[idx];
    g_sp[idx] = -sg * LOG2E;
    g_sq[idx] = sg * m * LOG2E;
    g_ss[idx] = log1pf(expf(sw[idx])) * smask[idx] * serev[idx];
}

// ---------------------------------------------------------------------------
// prep2: LayerNorm(6) + input affine folded -> inp [B*T][6].
// ---------------------------------------------------------------------------
__global__ void lnn_prep2(const float* __restrict__ x,
                          const float* __restrict__ ln_g, const float* __restrict__ ln_b,
                          const float* __restrict__ in_w, const float* __restrict__ in_b,
                          float* __restrict__ inp)
{
    int r = blockIdx.x * 256 + threadIdx.x;
    if (r >= 1024 * 96) return;
    const float* xp = x + r * 6;
    float v[6];
#pragma unroll
    for (int k = 0; k < 6; ++k) v[k] = xp[k];
    float m = (v[0] + v[1] + v[2] + v[3] + v[4] + v[5]) * (1.0f / 6.0f);
    float var = 0.f;
#pragma unroll
    for (int k = 0; k < 6; ++k) { float d = v[k] - m; var = fmaf(d, d, var); }
    var *= (1.0f / 6.0f);
    float rs = rsqrtf(var + 1e-5f);
    float* op = inp + r * 6;
#pragma unroll
    for (int k = 0; k < 6; ++k)
        op[k] = fmaf(fmaf((v[k] - m) * rs, ln_g[k], ln_b[k]), in_w[k], in_b[k]);
}

// ---------------------------------------------------------------------------
// main: 512 blocks x 512 threads (R10's winning shape: 8-wave blocks, 2/CU),
// each block = 2 batch elems. thread: j_slot=tid>>2 (rank), q=tid&3 (quarter);
// jj = perm[j_slot] (contiguous rank blocks per wave minimize wave-max trips).
// 12 entries pinned in 48 VGPRs (R11 lesson: 64 pinned + 2-batch spilled;
// R14 lesson: ext_vector v2f rewrite also spilled — scalar code only);
// entries 13-16 (cols with cnt>48, top waves only) in a 32KB LDS table under
// the wave-uniform kqm>12 guard. One ds_read_b64 per entry serves both batch
// elems (R12-validated: conflicts halve); cross-batch pair-rcp; dbuf vb2 ->
// 1 barrier/unfold; paired update rcp; eps dropped (den >= 3.1).
// ---------------------------------------------------------------------------
__global__ __launch_bounds__(512, 4)
void lnn_main_sp2(const float* __restrict__ inp, const float4* __restrict__ ent_g,
                  const float4* __restrict__ ov_g, const int* __restrict__ meta_g,
                  const float* __restrict__ g_sp, const float* __restrict__ g_sq,
                  const float* __restrict__ g_ss,
                  const float* __restrict__ g_gleak, const float* __restrict__ g_vleak,
                  const float* __restrict__ g_cm,
                  const float* __restrict__ g_ow, const float* __restrict__ g_ob,
                  float* __restrict__ outs)
{
    __shared__ float2 vb2[2][128];                 // [buf][i] = (v_b0, v_b1)
    __shared__ float4 ov_s[2048];                  // overflow entries, 32KB
    __shared__ float sp_s[6 * 132], sq_s[6 * 132], ss_s[6 * 132];
    __shared__ float cmt_s[128], gl_s[128], glvl_s[128];
    __shared__ float ow_s[64], ob_s[64];

    const int tid = threadIdx.x;
    const int j_slot = tid >> 2;
    const int q = tid & 3;
    const int jj = meta_g[128 + j_slot];
    const int cnt = meta_g[jj];
    const int kq_lane = (cnt + 3 - q) >> 2;

    if (tid < 512) ((float*)vb2)[tid] = 0.f;
    for (int i = tid; i < 2048; i += 512) ov_s[i] = ov_g[i];
    for (int idx = tid; idx < 768; idx += 512) {
        int k = idx >> 7, j = idx & 127;
        sp_s[k * 132 + j] = g_sp[idx];
        sq_s[k * 132 + j] = g_sq[idx];
        ss_s[k * 132 + j] = g_ss[idx];
    }
    if (tid < 128) {
        cmt_s[tid] = log1pf(expf(g_cm[tid])) * 6.0f;
        float gl = log1pf(expf(g_gleak[tid]));
        gl_s[tid] = gl;
        glvl_s[tid] = gl * g_vleak[tid];
    }
    if (tid < 64) { ow_s[tid] = g_ow[tid]; ob_s[tid] = g_ob[tid]; }

    // 12 entries -> named registers (zero-padded), pinned against remat (R8).
    const float4* eg = ent_g + ((jj << 2) + q) * 12;
#define ENT_LOAD(K) float4 e##K = eg[K];
    ENT_LOAD(0) ENT_LOAD(1) ENT_LOAD(2)  ENT_LOAD(3)
    ENT_LOAD(4) ENT_LOAD(5) ENT_LOAD(6)  ENT_LOAD(7)
    ENT_LOAD(8) ENT_LOAD(9) ENT_LOAD(10) ENT_LOAD(11)
#define ENT_PIN(K) asm volatile("" : "+v"(e##K.x), "+v"(e##K.y), "+v"(e##K.z), "+v"(e##K.w));
    ENT_PIN(0) ENT_PIN(1) ENT_PIN(2)  ENT_PIN(3)
    ENT_PIN(4) ENT_PIN(5) ENT_PIN(6)  ENT_PIN(7)
    ENT_PIN(8) ENT_PIN(9) ENT_PIN(10) ENT_PIN(11)

    // wave-uniform trip count (<=16)
    int kqm = kq_lane;
#pragma unroll
    for (int m = 1; m < 64; m <<= 1) kqm = max(kqm, __shfl_xor(kqm, m));
    kqm = __builtin_amdgcn_readfirstlane(kqm);

    __syncthreads();

    const float cmt = cmt_s[jj], glf = gl_s[jj], glvl = glvl_s[jj];
    const float osc = (jj < 64) ? ow_s[jj] : 0.f;
    const float obi = (jj < 64) ? ob_s[jj] : 0.f;
    const int bg = blockIdx.x;
    const float* ip0 = inp + (bg * 2) * 576;
    const float* ip1 = ip0 + 576;
    float* orow0 = outs + (((bg * 2) * 96) << 6) + jj;
    float vcur0 = 0.f, vcur1 = 0.f;
    const char* vbc = (const char*)&vb2[0][0];
    const int ovbase = ((jj << 2) + q) << 2;

    // one entry, both batch elems: 1 ds_read_b64, 2 exp2 + 1 rcp.
#define SIG_BODY(EX, EY, EZ, EW, OFS) { \
        float2 vv = *(const float2*)(vbc + (OFS) + __float_as_int(EW)); \
        float z0 = fmaf(EX, vv.x, EY); \
        float z1 = fmaf(EX, vv.y, EY); \
        float A = 1.0f + __builtin_amdgcn_exp2f(z0); \
        float B = 1.0f + __builtin_amdgcn_exp2f(z1); \
        float rP = __builtin_amdgcn_rcpf(A * B); \
        float s0 = B * rP; \
        float s1 = A * rP; \
        n0 = fmaf(EZ, s0, n0); d0 = fmaf(fabsf(EZ), s0, d0); \
        n1 = fmaf(EZ, s1, n1); d1 = fmaf(fabsf(EZ), s1, d1); }

#define ENT_DO(K, OFS) if (kqm > K) SIG_BODY(e##K.x, e##K.y, e##K.z, e##K.w, OFS)
#define OV_DO(K, OFS)  if (kqm > 12 + K) { float4 ee = ov_s[ovbase + K]; \
        SIG_BODY(ee.x, ee.y, ee.z, ee.w, OFS) }

#define ENT_BLOCK(OFS) \
        ENT_DO(0, OFS) ENT_DO(1, OFS) ENT_DO(2, OFS)  ENT_DO(3, OFS) \
        ENT_DO(4, OFS) ENT_DO(5, OFS) ENT_DO(6, OFS)  ENT_DO(7, OFS) \
        ENT_DO(8, OFS) ENT_DO(9, OFS) ENT_DO(10, OFS) ENT_DO(11, OFS) \
        OV_DO(0, OFS)  OV_DO(1, OFS)  OV_DO(2, OFS)   OV_DO(3, OFS)

    for (int t = 0; t < 96; ++t) {
        // sensory: q handles k=q (both elems) and q<2 also k=q+4; cross-batch pair.
        float sn0, sd0, sn1, sd1;
        {
            const int ko = q * 132 + jj;
            float z0 = fmaf(sp_s[ko], ip0[q], sq_s[ko]);
            float z1 = fmaf(sp_s[ko], ip1[q], sq_s[ko]);
            float A = 1.0f + __builtin_amdgcn_exp2f(z0);
            float B = 1.0f + __builtin_amdgcn_exp2f(z1);
            float rP = __builtin_amdgcn_rcpf(A * B);
            float s0 = B * rP, s1 = A * rP;
            float sv = ss_s[ko];
            sn0 = sv * s0; sd0 = fabsf(sv) * s0;
            sn1 = sv * s1; sd1 = fabsf(sv) * s1;
            if (q < 2) {
                const int k2 = q + 4;
                const int k2o = k2 * 132 + jj;
                float z2 = fmaf(sp_s[k2o], ip0[k2], sq_s[k2o]);
                float z3 = fmaf(sp_s[k2o], ip1[k2], sq_s[k2o]);
                float A2 = 1.0f + __builtin_amdgcn_exp2f(z2);
                float B2 = 1.0f + __builtin_amdgcn_exp2f(z3);
                float rP2 = __builtin_amdgcn_rcpf(A2 * B2);
                float s2 = B2 * rP2, s3 = A2 * rP2;
                float sv2 = ss_s[k2o];
                sn0 = fmaf(sv2, s2, sn0); sd0 = fmaf(fabsf(sv2), s2, sd0);
                sn1 = fmaf(sv2, s3, sn1); sd1 = fmaf(fabsf(sv2), s3, sd1);
            }
        }
        sn0 += __shfl_xor(sn0, 1); sd0 += __shfl_xor(sd0, 1);
        sn1 += __shfl_xor(sn1, 1); sd1 += __shfl_xor(sd1, 1);
        sn0 += __shfl_xor(sn0, 2); sd0 += __shfl_xor(sd0, 2);
        sn1 += __shfl_xor(sn1, 2); sd1 += __shfl_xor(sd1, 2);
        ip0 += 6; ip1 += 6;

        // 6 unfolds; u even: read buf0 write buf1; odd: read buf1 write buf0.
        for (int u = 0; u < 6; ++u) {
            float n0 = 0.f, d0 = 0.f, n1 = 0.f, d1 = 0.f;
            if (u & 1) { ENT_BLOCK(1024) } else { ENT_BLOCK(0) }
            n0 += __shfl_xor(n0, 1); d0 += __shfl_xor(d0, 1);
            n1 += __shfl_xor(n1, 1); d1 += __shfl_xor(d1, 1);
            n0 += __shfl_xor(n0, 2); d0 += __shfl_xor(d0, 2);
            n1 += __shfl_xor(n1, 2); d1 += __shfl_xor(d1, 2);
            float num0 = fmaf(cmt, vcur0, glvl) + n0 + sn0;
            float den0 = cmt + glf + d0 + sd0;
            float num1 = fmaf(cmt, vcur1, glvl) + n1 + sn1;
            float den1 = cmt + glf + d1 + sd1;
            float rD = __builtin_amdgcn_rcpf(den0 * den1);   // den >= 3.1 each
            vcur0 = num0 * den1 * rD;
            vcur1 = num1 * den0 * rD;
            if (q == 0) {
                ((float2*)((char*)vb2 + (((u & 1) ^ 1) << 10)))[jj] =
                    make_float2(vcur0, vcur1);
                if (u == 5 && jj < 64) {
                    orow0[0] = fmaf(vcur0, osc, obi);
                    orow0[6144] = fmaf(vcur1, osc, obi);
                }
            }
            __syncthreads();   // single barrier: writes visible, old-buf reads done
        }
        orow0 += 64;
    }
}

// ---------------------------------------------------------------------------
// attention pooling over T + classifier, one block per batch element.
// ---------------------------------------------------------------------------
__global__ __launch_bounds__(128)
void lnn_attn(const float* __restrict__ outs,
              const float* __restrict__ aw1, const float* __restrict__ ab1,
              const float* __restrict__ aw2,
              const float* __restrict__ cw1, const float* __restrict__ cb1,
              const float* __restrict__ cw2, const float* __restrict__ cb2,
              float* __restrict__ out)
{
    __shared__ float o_s[96 * 65];
    __shared__ float aw1_s[64 * 32];
    __shared__ float scr[96], attw[96], ctx_s[64], h2_s[128];

    const int b = blockIdx.x, tid = threadIdx.x;
    const float* ob = outs + b * 6144;
    for (int idx = tid; idx < 6144; idx += 128)
        o_s[(idx >> 6) * 65 + (idx & 63)] = ob[idx];
    for (int idx = tid; idx < 2048; idx += 128)
        aw1_s[idx] = aw1[idx];
    __syncthreads();

    if (tid < 96) {
        float h1[32];
#pragma unroll
        for (int m = 0; m < 32; ++m) h1[m] = ab1[m];
        for (int jj = 0; jj < 64; ++jj) {
            float ov = o_s[tid * 65 + jj];
#pragma unroll
            for (int m = 0; m < 32; ++m) h1[m] = fmaf(ov, aw1_s[(jj << 5) + m], h1[m]);
        }
        float sc = 0.f;
#pragma unroll
        for (int m = 0; m < 32; ++m) sc = fmaf(fmaxf(h1[m], 0.f), aw2[m], sc);
        scr[tid] = sc;
    }
    __syncthreads();

    float mx = -1e30f;
    for (int k = 0; k < 96; ++k) mx = fmaxf(mx, scr[k]);
    float sum = 0.f;
    for (int k = 0; k < 96; ++k) sum += expf(scr[k] - mx);
    if (tid < 96) attw[tid] = expf(scr[tid] - mx) / sum;
    __syncthreads();

    if (tid < 64) {
        float c = 0.f;
        for (int k = 0; k < 96; ++k) c = fmaf(attw[k], o_s[k * 65 + tid], c);
        ctx_s[tid] = c;
    }
    __syncthreads();

    {
        float a = cb1[tid];
        for (int jj = 0; jj < 64; ++jj) a = fmaf(ctx_s[jj], cw1[(jj << 7) + tid], a);
        h2_s[tid] = fmaxf(a, 0.f);
    }
    __syncthreads();

    if (tid < 100) {
        float a = cb2[tid];
        for (int m = 0; m < 128; ++m) a = fmaf(h2_s[m], cw2[m * 100 + tid], a);
        out[b * 100 + tid] = a;
    }
}

// ---------------------------------------------------------------------------
extern "C" void kernel_launch(void* const* d_in, const int* in_sizes, int n_in,
                              void* d_out, int out_size, void* d_ws, size_t ws_size,
                              hipStream_t stream)
{
    const float* x     = (const float*)d_in[0];
    const float* ln_g  = (const float*)d_in[1];
    const float* ln_b  = (const float*)d_in[2];
    const float* gleak = (const float*)d_in[3];
    const float* vleak = (const float*)d_in[4];
    const float* cm    = (const float*)d_in[5];
    const float* sigma = (const float*)d_in[6];
    const float* mu    = (const float*)d_in[7];
    const float* w     = (const float*)d_in[8];
    const float* erev  = (const float*)d_in[9];
    const float* ssig  = (const float*)d_in[10];
    const float* smu   = (const float*)d_in[11];
    const float* sw    = (const float*)d_in[12];
    const float* serev = (const float*)d_in[13];
    const float* in_w  = (const float*)d_in[14];
    const float* in_b  = (const float*)d_in[15];
    const float* ow    = (const float*)d_in[16];
    const float* obb   = (const float*)d_in[17];
    const float* aw1   = (const float*)d_in[18];
    const float* ab1   = (const float*)d_in[19];
    const float* aw2   = (const float*)d_in[20];
    const float* cw1   = (const float*)d_in[21];
    const float* cb1   = (const float*)d_in[22];
    const float* cw2   = (const float*)d_in[23];
    const float* cb2   = (const float*)d_in[24];
    const float* mask  = (const float*)d_in[25];
    const float* smask = (const float*)d_in[26];

    float* ws = (float*)d_ws;
    float*  inp   = ws;                          // 589824 f
    float*  sp    = ws + 589824;                 // 768
    float*  sq    = ws + 590592;                 // 768
    float*  ss    = ws + 591360;                 // 768
    float4* ent_g = (float4*)(ws + 592128);      // 128*4*12 float4 = 24576 f
    float4* ov_g  = (float4*)(ws + 616704);      // 128*4*4 float4  = 8192 f
    int*    meta  = (int*)(ws + 624896);         // 256 ints (pad 512)
    float*  outs  = ws + 625408;                 // 6291456 f

    lnn_prep_csc<<<1, 128, 0, stream>>>(sigma, mu, w, erev, mask, ent_g, ov_g, meta);
    lnn_prep_sens<<<1, 768, 0, stream>>>(ssig, smu, sw, serev, smask, sp, sq, ss);
    lnn_prep2<<<384, 256, 0, stream>>>(x, ln_g, ln_b, in_w, in_b, inp);
    lnn_main_sp2<<<512, 512, 0, stream>>>(inp, ent_g, ov_g, meta, sp, sq, ss,
                                          gleak, vleak, cm, ow, obb, outs);
    lnn_attn<<<1024, 128, 0, stream>>>(outs, aw1, ab1, aw2, cw1, cb1, cw2, cb2,
                                       (float*)d_out);
}